// Round 4
// baseline (174.449 us; speedup 1.0000x reference)
//
#include <hip/hip_runtime.h>
#include <math.h>

// Self-attention N=8192, D_in=256, D_out=128, fp32 in/out.
// fp32 accuracy via bf16 hi/lo split (3 MFMAs for QK^T, 2 for PV; P bf16-only).
// Structure: prep (split X/W) -> proj (bf16 GEMM, gload_lds staged) ->
// flash attn (32x32 MFMA, swapped QK^T, in-register softmax + permlane32_swap,
// KV-split=8, DOUBLE-BUFFERED KVBLK=32 with counted vmcnt(8), defer-max,
// setprio) -> merge.
// ws: [Qh Ql Kh Kl VTh VTl 12MB][mp lp 0.5MB][Op 32MB (aliases Xh/Xl/WT)]

typedef float f32x4 __attribute__((ext_vector_type(4)));
typedef float f32x16 __attribute__((ext_vector_type(16)));
typedef __bf16 bf16x8 __attribute__((ext_vector_type(8)));
typedef unsigned short ushort_t;
typedef ushort_t us4 __attribute__((ext_vector_type(4)));
typedef unsigned u32x2 __attribute__((ext_vector_type(2)));

#define N_TOK 8192
#define NSPLIT 8
#define KVB 32
#define NSTEP2 32  // 8192/8/32

static __device__ __forceinline__ f32x16 mfma32(bf16x8 a, bf16x8 b, f32x16 c) {
  return __builtin_amdgcn_mfma_f32_32x32x16_bf16(a, b, c, 0, 0, 0);
}
static __device__ __forceinline__ void f2split(float f, ushort_t& hi, ushort_t& lo) {
  __bf16 h = (__bf16)f;
  float rem = f - (float)h;
  __bf16 l2 = (__bf16)rem;
  hi = __builtin_bit_cast(ushort_t, h);
  lo = __builtin_bit_cast(ushort_t, l2);
}
static __device__ __forceinline__ void gload16(const void* g, void* l) {
  __builtin_amdgcn_global_load_lds(
      (const __attribute__((address_space(1))) unsigned*)g,
      (__attribute__((address_space(3))) unsigned*)l, 16, 0, 0);
}
static __device__ __forceinline__ unsigned cvtpk(float lo, float hi) {
  unsigned w;
  asm("v_cvt_pk_bf16_f32 %0, %1, %2" : "=v"(w) : "v"(lo), "v"(hi));
  return w;
}

// ---------------------------------------------------------------------------
// Kernel 0: split X (float4-vectorized) and W (transposed) into bf16 hi/lo.
// ---------------------------------------------------------------------------
__global__ __launch_bounds__(256) void prep_kernel(
    const float* __restrict__ X, const float* __restrict__ Wq,
    const float* __restrict__ Wk, const float* __restrict__ Wv,
    ushort_t* __restrict__ Xh, ushort_t* __restrict__ Xl,
    ushort_t* __restrict__ WTh, ushort_t* __restrict__ WTl) {
  int gid = blockIdx.x * 256 + threadIdx.x;
  if (gid < 524288) {  // 8192*256/4 float4s
    float4 v = reinterpret_cast<const float4*>(X)[gid];
    us4 h, l;
    ushort_t hh, ll;
    f2split(v.x, hh, ll); h[0] = hh; l[0] = ll;
    f2split(v.y, hh, ll); h[1] = hh; l[1] = ll;
    f2split(v.z, hh, ll); h[2] = hh; l[2] = ll;
    f2split(v.w, hh, ll); h[3] = hh; l[3] = ll;
    reinterpret_cast<us4*>(Xh)[gid] = h;
    reinterpret_cast<us4*>(Xl)[gid] = l;
  } else if (gid < 524288 + 98304) {
    int e = gid - 524288;
    int y = e >> 15, r = e & 32767;
    int k = r >> 7, c = r & 127;
    const float* W = (y == 0) ? Wq : (y == 1) ? Wk : Wv;
    ushort_t h, l;
    f2split(W[r], h, l);
    WTh[y * 32768 + c * 256 + k] = h;  // WT[y][c][k]
    WTl[y * 32768 + c * 256 + k] = l;
  }
}

// ---------------------------------------------------------------------------
// Kernel 1: QKV projection, 32x32x16 MFMA, split-3. grid (128, 3).
// Block: 64 tokens x 128 dout; 4 waves (2 row x 2 col). K sliced by 64.
// Q pre-scaled by (1/sqrt(128))*log2(e). V written transposed via LDS.
// ---------------------------------------------------------------------------
__global__ __launch_bounds__(256) void proj_kernel(
    const ushort_t* __restrict__ Xh, const ushort_t* __restrict__ Xl,
    const ushort_t* __restrict__ WTh, const ushort_t* __restrict__ WTl,
    ushort_t* __restrict__ Qh, ushort_t* __restrict__ Ql,
    ushort_t* __restrict__ Kh, ushort_t* __restrict__ Kl,
    ushort_t* __restrict__ VTh, ushort_t* __restrict__ VTl) {
  __shared__ __align__(16) char sm[49152];
  const int SXH = 0, SXL = 8192, SWH = 16384, SWL = 32768;
  int t = threadIdx.x, l = t & 63, wid = t >> 6;
  int c32 = l & 31, h = l >> 5;
  int wr = wid >> 1, wc = wid & 1;
  int t0 = blockIdx.x * 64, y = blockIdx.y;
  const ushort_t* WThy = WTh + y * 32768;
  const ushort_t* WTly = WTl + y * 32768;

  f32x16 zero = {};
  f32x16 acc[2];
  acc[0] = zero; acc[1] = zero;

  for (int sl = 0; sl < 4; ++sl) {
    int k0 = sl * 64;
    __syncthreads();
    // stage: Xh 8 chunks, Xl 8, WTh 16, WTl 16 (1KB each); 12 per wave.
    #pragma unroll
    for (int j = 0; j < 12; ++j) {
      int id = wid * 12 + j;
      const ushort_t* src;
      char* dst;
      if (id < 16) {
        const ushort_t* base = (id < 8) ? Xh : Xl;
        int c_ = id & 7;
        int row = 8 * c_ + (l >> 3);
        int slot = l & 7;
        src = base + (size_t)(t0 + row) * 256 + k0 + ((slot ^ (row & 7)) * 8);
        dst = sm + ((id < 8) ? SXH : SXL) + c_ * 1024 + l * 16;
      } else {
        const ushort_t* base = (id < 32) ? WThy : WTly;
        int c_ = (id - 16) & 15;
        int row = 8 * c_ + (l >> 3);
        int slot = l & 7;
        src = base + (size_t)row * 256 + k0 + ((slot ^ (row & 7)) * 8);
        dst = sm + ((id < 32) ? SWH : SWL) + c_ * 1024 + l * 16;
      }
      gload16(src, dst);
    }
    asm volatile("s_waitcnt vmcnt(0)" ::: "memory");
    __syncthreads();
    #pragma unroll
    for (int ks = 0; ks < 4; ++ks) {
      int ar = 32 * wr + c32;
      int ao = ar * 128 + (((2 * ks + h) ^ (ar & 7)) * 16);
      bf16x8 ah = *(const bf16x8*)(sm + SXH + ao);
      bf16x8 axl = *(const bf16x8*)(sm + SXL + ao);
      #pragma unroll
      for (int ct = 0; ct < 2; ++ct) {
        int bc = 64 * wc + 32 * ct + c32;
        int bo = bc * 128 + (((2 * ks + h) ^ (bc & 7)) * 16);
        bf16x8 bh = *(const bf16x8*)(sm + SWH + bo);
        bf16x8 bl2 = *(const bf16x8*)(sm + SWL + bo);
        acc[ct] = mfma32(ah, bh, acc[ct]);
        acc[ct] = mfma32(ah, bl2, acc[ct]);
        acc[ct] = mfma32(axl, bh, acc[ct]);
      }
    }
  }

  const float QS = 0.12751744f;  // (1/sqrt(128)) * log2(e)
  if (y < 2) {
    ushort_t* Hh = y ? Kh : Qh;
    ushort_t* Hl = y ? Kl : Ql;
    #pragma unroll
    for (int ct = 0; ct < 2; ++ct)
      #pragma unroll
      for (int r = 0; r < 16; ++r) {
        float v = acc[ct][r];
        if (y == 0) v *= QS;
        int rt = t0 + 32 * wr + (r & 3) + 8 * (r >> 2) + 4 * h;
        int cc = 64 * wc + 32 * ct + c32;
        ushort_t hh, ll;
        f2split(v, hh, ll);
        Hh[(size_t)rt * 128 + cc] = hh;
        Hl[(size_t)rt * 128 + cc] = ll;
      }
  } else {
    // V: transpose via LDS, write VT[128][8192] hi/lo coalesced.
    __syncthreads();
    #pragma unroll
    for (int ct = 0; ct < 2; ++ct)
      #pragma unroll
      for (int r = 0; r < 16; ++r) {
        float v = acc[ct][r];
        int rtl = 32 * wr + (r & 3) + 8 * (r >> 2) + 4 * h;
        int cc = 64 * wc + 32 * ct + c32;
        ushort_t hh, ll;
        f2split(v, hh, ll);
        *(ushort_t*)(sm + rtl * 272 + cc * 2) = hh;
        *(ushort_t*)(sm + 17408 + rtl * 272 + cc * 2) = ll;
      }
    __syncthreads();
    int cc = t >> 1, hs = t & 1;
    #pragma unroll
    for (int jj = 0; jj < 4; ++jj) {
      int r0 = hs * 32 + jj * 8;
      us4 a, b, a2, b2;
      #pragma unroll
      for (int e = 0; e < 4; ++e) {
        a[e]  = *(const ushort_t*)(sm + (r0 + e) * 272 + cc * 2);
        b[e]  = *(const ushort_t*)(sm + (r0 + 4 + e) * 272 + cc * 2);
        a2[e] = *(const ushort_t*)(sm + 17408 + (r0 + e) * 272 + cc * 2);
        b2[e] = *(const ushort_t*)(sm + 17408 + (r0 + 4 + e) * 272 + cc * 2);
      }
      *(us4*)(VTh + (size_t)cc * N_TOK + t0 + r0) = a;
      *(us4*)(VTh + (size_t)cc * N_TOK + t0 + r0 + 4) = b;
      *(us4*)(VTl + (size_t)cc * N_TOK + t0 + r0) = a2;
      *(us4*)(VTl + (size_t)cc * N_TOK + t0 + r0 + 4) = b2;
    }
  }
}

// ---------------------------------------------------------------------------
// Kernel 2: flash attention. 512 blocks x 256 threads, KV-split=8 (bid&7).
// Block: 128 q (4 waves x 32), 32 steps of 32 keys, DOUBLE-BUFFERED staging:
// stage(t+1) issued before compute(t); counted vmcnt(8) so the drain hides
// under compute. Wave wid stages one of {Kh,Kl,Vh,Vl} (8 x 1KB each).
// Swapped QK^T -> in-register softmax (defer-max THR=8) -> permlane P ->
// O^T = V^T * P^T. LDS 2 x 32KB, 2 blocks/CU.
// ---------------------------------------------------------------------------
__global__ __launch_bounds__(256, 2) void attn_kernel(
    const ushort_t* __restrict__ Qh, const ushort_t* __restrict__ Ql,
    const ushort_t* __restrict__ Kh, const ushort_t* __restrict__ Kl,
    const ushort_t* __restrict__ VTh, const ushort_t* __restrict__ VTl,
    float* __restrict__ Op, float* __restrict__ mp, float* __restrict__ lp) {
  extern __shared__ __align__(16) char sm[];
  // per buffer 32KB: [Kh 8K][Kl 8K][Vh 8K][Vl 8K]; buffers at 0 and 32768.
  int t = threadIdx.x, l = t & 63, wid = t >> 6;
  int c32 = l & 31, h = l >> 5;
  int bid = blockIdx.x;
  int split = bid & 7, qt = bid >> 3;
  int qb = qt * 128, kv0 = split * 1024;
  int q_lane = qb + wid * 32 + c32;

  // Q fragments (B-operand: lane holds Q[q=l&31][d = 16ks + 8h + j])
  bf16x8 qfh[8], qfl[8];
  #pragma unroll
  for (int ks = 0; ks < 8; ++ks) {
    qfh[ks] = *(const bf16x8*)(Qh + (size_t)q_lane * 128 + ks * 16 + h * 8);
    qfl[ks] = *(const bf16x8*)(Ql + (size_t)q_lane * 128 + ks * 16 + h * 8);
  }

  // Staging setup: wave wid owns {0:Kh, 1:Kl, 2:VTh, 3:VTl}; 8 x 1KB chunks.
  // Linear LDS dest + inverse-swizzled global source (rule 21).
  const ushort_t* gbase;
  int stepstride;
  int offs[8];
  if (wid < 2) {
    gbase = ((wid == 0) ? Kh : Kl) + (size_t)kv0 * 128;
    stepstride = KVB * 128;
    #pragma unroll
    for (int j = 0; j < 8; ++j) {
      int row = 4 * j + (l >> 4);
      offs[j] = row * 128 + (((l & 15) ^ (row & 15)) * 8);
    }
  } else {
    gbase = ((wid == 2) ? VTh : VTl) + kv0;
    stepstride = KVB;
    #pragma unroll
    for (int j = 0; j < 8; ++j) {
      int d = 16 * j + (l >> 2);
      offs[j] = d * N_TOK + (((l & 3) ^ ((l >> 2) & 3)) * 8);
    }
  }
  char* ldsbase = sm + wid * 8192 + l * 16;

  f32x16 zero = {};
  f32x16 od[4];
  #pragma unroll
  for (int dt = 0; dt < 4; ++dt) od[dt] = zero;
  float m = -INFINITY, lsum = 0.f;

  // prologue: stage tile 0 into buffer 0
  {
    const ushort_t* sb = gbase;
    #pragma unroll
    for (int j = 0; j < 8; ++j) gload16(sb + offs[j], ldsbase + j * 1024);
  }

  for (int s = 0; s < NSTEP2; ++s) {
    int cur = s & 1;
    // issue next tile's stage into the other buffer (wraps at end: harmless)
    {
      const ushort_t* sb = gbase + (size_t)((s + 1) & (NSTEP2 - 1)) * stepstride;
      char* db = ldsbase + (cur ^ 1) * 32768;
      #pragma unroll
      for (int j = 0; j < 8; ++j) gload16(sb + offs[j], db + j * 1024);
    }
    // wait only on the PREVIOUS stage's 8 loads (a full phase old)
    asm volatile("s_waitcnt vmcnt(8)" ::: "memory");
    __syncthreads();

    const char* bK = sm + cur * 32768;
    const char* bV = bK + 16384;

    // S^T = K * Q^T (split-3): 32 keys x 32 q; col = q, row = key.
    f32x16 sc = zero;
    __builtin_amdgcn_s_setprio(1);
    #pragma unroll
    for (int ks = 0; ks < 8; ++ks) {
      int so = ((2 * ks + h) ^ (c32 & 15)) * 16;
      bf16x8 ah = *(const bf16x8*)(bK + c32 * 256 + so);
      bf16x8 al2 = *(const bf16x8*)(bK + 8192 + c32 * 256 + so);
      sc = mfma32(ah, qfh[ks], sc);
      sc = mfma32(ah, qfl[ks], sc);
      sc = mfma32(al2, qfh[ks], sc);
    }
    __builtin_amdgcn_s_setprio(0);

    // online softmax in log2 units; defer-max (THR = 8 -> P <= 256)
    float pm = sc[0];
    #pragma unroll
    for (int r = 1; r < 16; ++r) pm = fmaxf(pm, sc[r]);
    pm = fmaxf(pm, __shfl_xor(pm, 32));
    if (!__all(pm <= m + 8.0f)) {
      float mn = fmaxf(m, pm);
      float al = exp2f(m - mn);
      m = mn;
      lsum *= al;
      #pragma unroll
      for (int dt = 0; dt < 4; ++dt) od[dt] *= al;
    }
    float ps = 0.f;
    #pragma unroll
    for (int r = 0; r < 16; ++r) { sc[r] = exp2f(sc[r] - m); ps += sc[r]; }
    lsum += ps;

    // P^T B-fragments in-register: 8 cvt_pk + 4 permlane32_swap.
    bf16x8 pf[2];
    #pragma unroll
    for (int ks = 0; ks < 2; ++ks) {
      int r0 = 8 * ks;
      unsigned A0 = cvtpk(sc[r0 + 0], sc[r0 + 1]);
      unsigned A1 = cvtpk(sc[r0 + 2], sc[r0 + 3]);
      unsigned B0 = cvtpk(sc[r0 + 4], sc[r0 + 5]);
      unsigned B1 = cvtpk(sc[r0 + 6], sc[r0 + 7]);
      u32x2 s0 = __builtin_amdgcn_permlane32_swap(A0, B0, false, false);
      u32x2 s1 = __builtin_amdgcn_permlane32_swap(A1, B1, false, false);
      union { unsigned u[4]; bf16x8 v; } cvt;
      cvt.u[0] = s0[0]; cvt.u[1] = s1[0]; cvt.u[2] = s0[1]; cvt.u[3] = s1[1];
      pf[ks] = cvt.v;
    }

    // O^T += V^T * P^T (V hi/lo, P bf16). V tile [128 d][32 keys], 64B rows.
    __builtin_amdgcn_s_setprio(1);
    #pragma unroll
    for (int ks = 0; ks < 2; ++ks) {
      #pragma unroll
      for (int dt = 0; dt < 4; ++dt) {
        int row = 32 * dt + c32;
        int so2 = row * 64 + (((2 * ks + h) ^ (row & 3)) * 16);
        bf16x8 vh = *(const bf16x8*)(bV + so2);
        bf16x8 vl2 = *(const bf16x8*)(bV + 8192 + so2);
        od[dt] = mfma32(vh, pf[ks], od[dt]);
        od[dt] = mfma32(vl2, pf[ks], od[dt]);
      }
    }
    __builtin_amdgcn_s_setprio(0);
    __syncthreads();  // all waves done reading buf[cur] -> next stage may overwrite
  }

  lsum += __shfl_xor(lsum, 32);
  // store O^T partial: Op[split][d][q] (coalesced along q)
  #pragma unroll
  for (int dt = 0; dt < 4; ++dt)
    #pragma unroll
    for (int r = 0; r < 16; ++r) {
      int d = 32 * dt + (r & 3) + 8 * (r >> 2) + 4 * h;
      Op[(size_t)(split * 128 + d) * N_TOK + q_lane] = od[dt][r];
    }
  if (h == 0) {
    mp[split * N_TOK + q_lane] = m;
    lp[split * N_TOK + q_lane] = lsum;
  }
}

// ---------------------------------------------------------------------------
// Kernel 3: merge 8 partials. Block = 32 q x 128 d, LDS transpose so both
// Op reads (along q) and out writes (along d) are coalesced.
// ---------------------------------------------------------------------------
__global__ __launch_bounds__(256) void merge_kernel(
    const float* __restrict__ Op, const float* __restrict__ mp,
    const float* __restrict__ lp, float* __restrict__ out) {
  __shared__ float accs[32][129];
  __shared__ float Ls[32];
  int t = threadIdx.x;
  int q0 = blockIdx.x * 32;
  int ql = t & 31, dr = t >> 5;
  float mm[NSPLIT], ll[NSPLIT];
  #pragma unroll
  for (int s2 = 0; s2 < NSPLIT; ++s2) {
    mm[s2] = mp[s2 * N_TOK + q0 + ql];
    ll[s2] = lp[s2 * N_TOK + q0 + ql];
  }
  float M = mm[0];
  #pragma unroll
  for (int s2 = 1; s2 < NSPLIT; ++s2) M = fmaxf(M, mm[s2]);
  float w[NSPLIT], L = 0.f;
  #pragma unroll
  for (int s2 = 0; s2 < NSPLIT; ++s2) { w[s2] = exp2f(mm[s2] - M); L += w[s2] * ll[s2]; }
  if (dr == 0) Ls[ql] = L;
  for (int dd = dr; dd < 128; dd += 8) {
    float a = 0.f;
    #pragma unroll
    for (int s2 = 0; s2 < NSPLIT; ++s2)
      a += w[s2] * Op[(size_t)(s2 * 128 + dd) * N_TOK + q0 + ql];
    accs[ql][dd] = a;
  }
  __syncthreads();
  int q = t >> 3, db = (t & 7) * 16;
  float inv = 1.0f / Ls[q];
  #pragma unroll
  for (int jj = 0; jj < 4; ++jj) {
    f32x4 v;
    #pragma unroll
    for (int e = 0; e < 4; ++e) v[e] = accs[q][db + jj * 4 + e] * inv;
    *reinterpret_cast<f32x4*>(out + (size_t)(q0 + q) * 128 + db + jj * 4) = v;
  }
}

// ---------------------------------------------------------------------------
extern "C" void kernel_launch(void* const* d_in, const int* in_sizes, int n_in,
                              void* d_out, int out_size, void* d_ws, size_t ws_size,
                              hipStream_t stream) {
  (void)in_sizes; (void)n_in; (void)out_size; (void)ws_size;
  const float* X  = (const float*)d_in[0];
  const float* Wq = (const float*)d_in[1];
  const float* Wk = (const float*)d_in[2];
  const float* Wv = (const float*)d_in[3];
  float* out = (float*)d_out;
  char* ws = (char*)d_ws;

  const size_t MB = 1048576;
  ushort_t* Qh  = (ushort_t*)(ws + 0 * MB);
  ushort_t* Ql  = (ushort_t*)(ws + 2 * MB);
  ushort_t* Kh  = (ushort_t*)(ws + 4 * MB);
  ushort_t* Kl  = (ushort_t*)(ws + 6 * MB);
  ushort_t* VTh = (ushort_t*)(ws + 8 * MB);
  ushort_t* VTl = (ushort_t*)(ws + 10 * MB);
  float* mpp = (float*)(ws + 12 * MB);
  float* lpp = (float*)(ws + 12 * MB + 262144);
  float* Op  = (float*)(ws + 12 * MB + 524288);   // 32 MB
  // prep-only region, aliased inside Op (dead before attn writes Op):
  ushort_t* Xh  = (ushort_t*)(ws + 12 * MB + 524288);
  ushort_t* Xl  = (ushort_t*)(ws + 16 * MB + 524288);
  ushort_t* WTh = (ushort_t*)(ws + 20 * MB + 524288);
  ushort_t* WTl = (ushort_t*)(ws + 20 * MB + 524288 + 196608);

  (void)hipFuncSetAttribute((const void*)attn_kernel,
                            hipFuncAttributeMaxDynamicSharedMemorySize, 65536);

  prep_kernel<<<2432, 256, 0, stream>>>(X, Wq, Wk, Wv, Xh, Xl, WTh, WTl);
  proj_kernel<<<dim3(128, 3), 256, 0, stream>>>(Xh, Xl, WTh, WTl,
                                                Qh, Ql, Kh, Kl, VTh, VTl);
  attn_kernel<<<512, 256, 65536, stream>>>(Qh, Ql, Kh, Kl, VTh, VTl, Op, mpp, lpp);
  merge_kernel<<<256, 256, 0, stream>>>(Op, mpp, lpp, out);
}